// Round 1
// baseline (247.526 us; speedup 1.0000x reference)
//
#include <hip/hip_runtime.h>

#define N_RES   2000000
#define HIDDEN  128
#define BLK     256

// ---------------------------------------------------------------------------
// Fused kernel.
//  - Every block redundantly computes the tiny MLP -> tv (6 floats). W1/W2
//    are L2-resident (27 KB), so this is ~60 FMA/thread hidden under the
//    streaming pos loads that are issued first.
//  - Per-residue: closed-form window indices, product over 10 windows,
//    2-way softmax, attn (float2, coalesced), translation staged in LDS.
//  - Cooperative epilogue: block's 2304-float pos slice is 16B-aligned ->
//    float4 load/add/store (3 chunks/thread); out_trans written as float4
//    straight from LDS. Every VMEM instruction touches 4 cache lines.
// ---------------------------------------------------------------------------
__global__ __launch_bounds__(BLK, 4) void fused_kernel(
    const float* __restrict__ weights,   // (nbw, 2)
    const float* __restrict__ latent,    // 6
    const float* __restrict__ features,  // 2*50
    const float* __restrict__ W1,        // 53*128
    const float* __restrict__ b1,        // 128
    const float* __restrict__ W2,        // 128*3
    const float* __restrict__ b2,        // 3
    const float* __restrict__ lf,        // 3*3
    const float* __restrict__ pos,       // (6M, 3)
    float* __restrict__ out_pos,         // 18M
    float* __restrict__ out_attn,        // 4M
    float* __restrict__ out_trans)       // 6M
{
    __shared__ float h[2][HIDDEN];
    __shared__ float sv[6];
    __shared__ float tvs[6];
    __shared__ __align__(16) float t_lds[3 * BLK];

    const int tid  = threadIdx.x;
    const int r0   = blockIdx.x * BLK;
    const int r    = r0 + tid;
    const int nres = min(BLK, N_RES - r0);   // 256, last block 128
    const int nch  = (9 * nres) >> 2;        // 576, last block 288 (always /4)

    // ---- issue streaming pos loads first (float4, fully coalesced) --------
    const float4* __restrict__ pos4 = (const float4*)(pos + 9ll * r0); // 9216B*blk: 16B aligned
    float4 pA = make_float4(0.f,0.f,0.f,0.f);
    float4 pB = pA, pC = pA;
    if (tid            < nch) pA = pos4[tid];
    if (tid +     BLK  < nch) pB = pos4[tid + BLK];
    if (tid + 2 * BLK  < nch) pC = pos4[tid + 2 * BLK];

    // ---- per-block tiny MLP (redundant; hidden under the loads) -----------
    {
        const int d = tid >> 7, j = tid & 127;   // h[d][j]
        float acc = b1[j];
        #pragma unroll
        for (int k = 0; k < 50; ++k)
            acc += features[d * 50 + k] * W1[k * HIDDEN + j];
        #pragma unroll
        for (int k = 0; k < 3; ++k)
            acc += latent[d * 3 + k] * W1[(50 + k) * HIDDEN + j];
        h[d][j] = fmaxf(acc, 0.0f);
    }
    __syncthreads();
    {
        // s[dd][c] = b2[c] + sum_k h[dd][k] * W2[k*3+c]
        // 192 active threads: (dd, c, l<32); 32-lane group reduce via shfl.
        const int dd   = tid >> 7;
        const int rest = tid & 127;
        const int c    = rest >> 5;              // 0..3 (3 idle)
        const int l    = rest & 31;
        if (c < 3) {
            float a = 0.f;
            #pragma unroll
            for (int m = 0; m < 4; ++m)
                a += h[dd][l + 32 * m] * W2[(l + 32 * m) * 3 + c];
            #pragma unroll
            for (int off = 16; off >= 1; off >>= 1)
                a += __shfl_xor(a, off, 64);     // partner stays in same 32-group
            if (l == 0) sv[dd * 3 + c] = a + b2[c];
        }
    }
    __syncthreads();
    if (tid < 6) {
        const int dd = tid / 3, c = tid % 3;
        // tv[dd][c] = sum_k s[dd][k] * lf[c][k]   (@ lf^T)
        float a = 0.f;
        #pragma unroll
        for (int k = 0; k < 3; ++k)
            a += sv[dd * 3 + k] * lf[c * 3 + k];
        tvs[tid] = a;
    }
    __syncthreads();

    // ---- per-residue attn + translation -----------------------------------
    float t0 = 0.f, t1 = 0.f, t2 = 0.f;
    if (r < N_RES) {
        // closed-form window indices: start = ceil(max(r-9,0)/10)
        const int raw   = max(r - 9, 0);
        const int start = (raw + 9) / 10;
        const float2* wbase = (const float2*)(weights) + start;
        float p0 = 1.0f, p1 = 1.0f;
        #pragma unroll
        for (int j = 0; j < 10; ++j) {
            const float2 w = wbase[j];
            p0 *= w.x;
            p1 *= w.y;
        }
        const float m   = fmaxf(p0, p1);
        const float e0  = __expf(p0 - m);
        const float e1  = __expf(p1 - m);
        const float inv = 1.0f / (e0 + e1);
        const float a0  = e0 * inv;
        const float a1  = e1 * inv;

        ((float2*)out_attn)[r] = make_float2(a0, a1);   // 8B/lane, coalesced

        t0 = a0 * tvs[0] + a1 * tvs[3];
        t1 = a0 * tvs[1] + a1 * tvs[4];
        t2 = a0 * tvs[2] + a1 * tvs[5];
    }
    t_lds[3 * tid + 0] = t0;     // stride-3: worst 2-way bank alias (free)
    t_lds[3 * tid + 1] = t1;
    t_lds[3 * tid + 2] = t2;
    __syncthreads();

    // ---- coalesced float4 epilogue ----------------------------------------
    // out_trans: 3*nres floats (768/384), base 3072B*blk -> 16B aligned.
    const int ntr = (3 * nres) >> 2;
    if (tid < ntr)
        ((float4*)(out_trans + 3ll * r0))[tid] = ((const float4*)t_lds)[tid];

    // out_pos = pos + repeat(trans): float4 chunks, component = (idx%9)%3.
    float4* __restrict__ o4 = (float4*)(out_pos + 9ll * r0);
    auto addt = [&](float4 v, int c) -> float4 {
        float* vp = (float*)&v;
        const int e = 4 * c;
        #pragma unroll
        for (int k = 0; k < 4; ++k) {
            const int idx = e + k;           // block-local element, < 2304
            const int rl  = idx / 9;         // magic-mul
            int cm = idx - 9 * rl;           // 0..8
            cm = (cm >= 6) ? cm - 6 : ((cm >= 3) ? cm - 3 : cm);
            vp[k] += t_lds[3 * rl + cm];
        }
        return v;
    };
    if (tid            < nch) o4[tid          ] = addt(pA, tid          );
    if (tid +     BLK  < nch) o4[tid +     BLK] = addt(pB, tid +     BLK);
    if (tid + 2 * BLK  < nch) o4[tid + 2 * BLK] = addt(pC, tid + 2 * BLK);
}

extern "C" void kernel_launch(void* const* d_in, const int* in_sizes, int n_in,
                              void* d_out, int out_size, void* d_ws, size_t ws_size,
                              hipStream_t stream) {
    const float* weights  = (const float*)d_in[0];
    const float* latent   = (const float*)d_in[1];
    const float* features = (const float*)d_in[2];
    const float* W1       = (const float*)d_in[3];
    const float* b1       = (const float*)d_in[4];
    const float* W2       = (const float*)d_in[5];
    const float* b2       = (const float*)d_in[6];
    const float* lf       = (const float*)d_in[7];
    const float* pos      = (const float*)d_in[8];
    // d_in[9] (bs_per_res) intentionally unread: indices recomputed in-kernel.

    float* out = (float*)d_out;

    const int blocks = (N_RES + BLK - 1) / BLK;
    fused_kernel<<<blocks, BLK, 0, stream>>>(
        weights, latent, features, W1, b1, W2, b2, lf, pos,
        out,                 // new_atom_positions: [0, 18M)
        out + 18000000,      // attn:               [18M, 22M)
        out + 22000000);     // translation:        [22M, 28M)
}

// Round 4
// 230.952 us; speedup vs baseline: 1.0718x; 1.0718x over previous
//
#include <hip/hip_runtime.h>

#define N_RES   2000000
#define HIDDEN  128
#define BLK     256

// ---------------------------------------------------------------------------
// Kernel A: the tiny MLP + frame transform (one block; runs in a few µs).
//   fl (2,53) = concat(features(2,50), latent.reshape(2,3))
//   h  = relu(fl @ W1 + b1)          (2,128)
//   s  = h @ W2 + b2                 (2,3)
//   tv = s @ local_frame^T           (2,3)  -> d_ws
// ---------------------------------------------------------------------------
__global__ void mlp_kernel(const float* __restrict__ latent,    // 6
                           const float* __restrict__ features,  // 2*50
                           const float* __restrict__ W1,        // 53*128
                           const float* __restrict__ b1,        // 128
                           const float* __restrict__ W2,        // 128*3
                           const float* __restrict__ b2,        // 3
                           const float* __restrict__ lf,        // 3*3
                           float* __restrict__ tv_out)          // 6
{
    __shared__ float h[2][HIDDEN];
    __shared__ float s[2][3];
    const int tid = threadIdx.x;
    const int d = tid >> 7;          // 0..1
    const int j = tid & 127;         // 0..127

    float acc = b1[j];
    #pragma unroll 10
    for (int k = 0; k < 50; ++k)
        acc += features[d * 50 + k] * W1[k * HIDDEN + j];
    #pragma unroll
    for (int k = 0; k < 3; ++k)
        acc += latent[d * 3 + k] * W1[(50 + k) * HIDDEN + j];
    h[d][j] = fmaxf(acc, 0.0f);
    __syncthreads();

    if (tid < 6) {
        const int dd = tid / 3, c = tid % 3;
        float a = b2[c];
        #pragma unroll 16
        for (int k = 0; k < HIDDEN; ++k)
            a += h[dd][k] * W2[k * 3 + c];
        s[dd][c] = a;
    }
    __syncthreads();

    if (tid < 6) {
        const int dd = tid / 3, c = tid % 3;
        // tv[dd][c] = sum_k s[dd][k] * lf[c][k]   (note: @ lf^T)
        float a = 0.0f;
        #pragma unroll
        for (int k = 0; k < 3; ++k)
            a += s[dd][k] * lf[c * 3 + k];
        tv_out[dd * 3 + c] = a;
    }
}

// ---------------------------------------------------------------------------
// Kernel B: pure streaming deform. No MLP, no W1 traffic, ONE __syncthreads.
//  - closed-form window indices: start = ceil(max(r-9,0)/10)
//  - pos float4 loads issued first (fills the memory pipe immediately)
//  - attn: float2 store (coalesced)
//  - translation staged in LDS (stride-3: 2-way bank alias = free),
//    then float4 epilogue for out_trans and out_pos: every VMEM instruction
//    touches exactly 4 cache lines.
// ---------------------------------------------------------------------------
__global__ __launch_bounds__(BLK) void deform_kernel(
    const float* __restrict__ weights,   // (nbw, 2)
    const float* __restrict__ pos,       // (6M, 3)
    const float* __restrict__ tv,        // (2, 3) in d_ws
    float* __restrict__ out_pos,         // 18M
    float* __restrict__ out_attn,        // 4M
    float* __restrict__ out_trans)       // 6M
{
    __shared__ __align__(16) float t_lds[3 * BLK];

    const int tid  = threadIdx.x;
    const int r0   = blockIdx.x * BLK;
    const int r    = r0 + tid;
    const int nres = min(BLK, N_RES - r0);   // 256, last block 128
    const int nch  = (9 * nres) >> 2;        // 576, last block 288

    // ---- issue streaming pos loads first (float4, fully coalesced) --------
    const float4* __restrict__ pos4 = (const float4*)(pos + 9ll * r0);
    float4 pA = make_float4(0.f, 0.f, 0.f, 0.f);
    float4 pB = pA, pC = pA;
    if (tid            < nch) pA = pos4[tid];
    if (tid +     BLK  < nch) pB = pos4[tid + BLK];
    if (tid + 2 * BLK  < nch) pC = pos4[tid + 2 * BLK];

    // tv: 6 uniform floats, L2-resident broadcast loads.
    const float tv0 = tv[0], tv1 = tv[1], tv2 = tv[2];
    const float tv3 = tv[3], tv4 = tv[4], tv5 = tv[5];

    // ---- per-residue attn + translation -----------------------------------
    float t0 = 0.f, t1 = 0.f, t2 = 0.f;
    if (r < N_RES) {
        const int raw   = max(r - 9, 0);
        const int start = (raw + 9) / 10;
        const float2* wbase = (const float2*)(weights) + start;
        float p0 = 1.0f, p1 = 1.0f;
        #pragma unroll
        for (int j = 0; j < 10; ++j) {
            const float2 w = wbase[j];
            p0 *= w.x;
            p1 *= w.y;
        }
        const float m   = fmaxf(p0, p1);
        const float e0  = __expf(p0 - m);
        const float e1  = __expf(p1 - m);
        const float inv = 1.0f / (e0 + e1);
        const float a0  = e0 * inv;
        const float a1  = e1 * inv;

        ((float2*)out_attn)[r] = make_float2(a0, a1);   // 8B/lane, coalesced

        t0 = a0 * tv0 + a1 * tv3;
        t1 = a0 * tv1 + a1 * tv4;
        t2 = a0 * tv2 + a1 * tv5;
    }
    t_lds[3 * tid + 0] = t0;
    t_lds[3 * tid + 1] = t1;
    t_lds[3 * tid + 2] = t2;
    __syncthreads();

    // ---- coalesced float4 epilogue ----------------------------------------
    // out_trans: 3*nres floats (768/384), base 3072B*blk -> 16B aligned.
    const int ntr = (3 * nres) >> 2;
    if (tid < ntr)
        ((float4*)(out_trans + 3ll * r0))[tid] = ((const float4*)t_lds)[tid];

    // out_pos = pos + repeat(trans). One /9 per chunk, running (rl, cm).
    float4* __restrict__ o4 = (float4*)(out_pos + 9ll * r0);
    auto addt = [&](float4 v, int c) -> float4 {
        float* vp = (float*)&v;
        const int e = 4 * c;            // block-local element, < 2304
        int rl = e / 9;                 // one magic-mul per chunk
        int cm = e - 9 * rl;            // 0..8
        #pragma unroll
        for (int k = 0; k < 4; ++k) {
            const int c3 = (cm >= 6) ? cm - 6 : ((cm >= 3) ? cm - 3 : cm);
            vp[k] += t_lds[3 * rl + c3];
            if (++cm == 9) { cm = 0; ++rl; }
        }
        return v;
    };
    if (tid            < nch) o4[tid          ] = addt(pA, tid          );
    if (tid +     BLK  < nch) o4[tid +     BLK] = addt(pB, tid +     BLK);
    if (tid + 2 * BLK  < nch) o4[tid + 2 * BLK] = addt(pC, tid + 2 * BLK);
}

extern "C" void kernel_launch(void* const* d_in, const int* in_sizes, int n_in,
                              void* d_out, int out_size, void* d_ws, size_t ws_size,
                              hipStream_t stream) {
    const float* weights  = (const float*)d_in[0];
    const float* latent   = (const float*)d_in[1];
    const float* features = (const float*)d_in[2];
    const float* W1       = (const float*)d_in[3];
    const float* b1       = (const float*)d_in[4];
    const float* W2       = (const float*)d_in[5];
    const float* b2       = (const float*)d_in[6];
    const float* lf       = (const float*)d_in[7];
    const float* pos      = (const float*)d_in[8];
    // d_in[9] (bs_per_res) intentionally unread: indices recomputed in-kernel.

    float* out = (float*)d_out;
    float* tvw = (float*)d_ws;   // 6 floats of scratch

    mlp_kernel<<<1, 256, 0, stream>>>(latent, features, W1, b1, W2, b2, lf, tvw);

    const int blocks = (N_RES + BLK - 1) / BLK;
    deform_kernel<<<blocks, BLK, 0, stream>>>(
        weights, pos, tvw,
        out,                 // new_atom_positions: [0, 18M)
        out + 18000000,      // attn:               [18M, 22M)
        out + 22000000);     // translation:        [22M, 28M)
}